// Round 10
// baseline (108.038 us; speedup 1.0000x reference)
//
#include <hip/hip_runtime.h>

typedef unsigned long long u64;
typedef unsigned int u32;

#define W    4096
#define NT   256
#define PT   16          // contiguous elements per thread
#define NCH  128         // chunks of size 32 (== dist fast path)
#define D32  32
#define RFIX 128         // fixed round count (>= worst-case depth 126); diagnostic

__global__ __launch_bounds__(NT) void extrema_nms_kernel(
    const float* __restrict__ x,
    const int*   __restrict__ dist_p,
    float*       __restrict__ out)
{
    const int sig = blockIdx.x;
    const float* xg = x + (size_t)sig * W;
    float*       og = out + (size_t)sig * W;
    const int dist = *dist_p;

    __shared__ __align__(16) float xs[W];       // 16 KB, read-only after init
    __shared__ __align__(16) u64   HM[NT + 4];  // padded half-maxes; pads = 0
    __shared__ int   KF[NCH + 2];               // padded killflags, round-stamped
    __shared__ int   kept[NCH];                 // keeper position+1, 0 = none
    __shared__ int   LF;                        // round-stamped live flag
    __shared__ __align__(16) u64   key[W];      // (generic fallback only)
    __shared__ u64   red[NT / 64];              // (generic fallback only)

    const int tid = threadIdx.x;

    // coalesced float4 staging of x into LDS
    {
        const float4* xg4 = (const float4*)xg;
        float4*       xs4 = (float4*)xs;
        #pragma unroll
        for (int v = tid; v < W / 4; v += NT) xs4[v] = xg4[v];
    }
    if (tid < 2) { HM[tid] = 0ull; HM[NT + 2 + tid] = 0ull; }  // edge pads
    if (tid < NCH + 2) KF[tid] = 0;
    if (tid < NCH) kept[tid] = 0;
    if (tid == 0) LF = 0;
    __syncthreads();

    if (dist == D32) {
        // ---------- fast path: chunk(=dist)-decomposed parallel greedy NMS ----------
        const int c    = tid >> 1;      // own chunk (2 threads per chunk)
        const int base = tid * PT;      // first owned element

        // extrema keys built from registers (explicit float4 loads, no rescans)
        u64 kr[PT];
        {
            const float4* xs4 = (const float4*)xs;
            const int b4 = tid * 4;
            const float4 q0 = xs4[b4], q1 = xs4[b4 + 1], q2 = xs4[b4 + 2], q3 = xs4[b4 + 3];
            float f[PT + 2];
            f[1] = q0.x; f[2] = q0.y; f[3] = q0.z; f[4] = q0.w;
            f[5] = q1.x; f[6] = q1.y; f[7] = q1.z; f[8] = q1.w;
            f[9] = q2.x; f[10] = q2.y; f[11] = q2.z; f[12] = q2.w;
            f[13] = q3.x; f[14] = q3.y; f[15] = q3.z; f[16] = q3.w;
            f[0]      = (base > 0)       ? xs[base - 1]  : __int_as_float(0x7f800000); // +inf -> left=true at i=0
            f[PT + 1] = (base + PT < W)  ? xs[base + PT] : q3.w;                        // x==x -> right=false at i=W-1
            #pragma unroll
            for (int j = 0; j < PT; ++j) {
                const float xi = f[j + 1];
                const bool right = f[j + 2] > xi;   // (x[i+1]-x[i]) > 0, pad-right -> false
                const bool left  = xi <= f[j];      // (x[i]-x[i-1]) <= 0, pad-left -> true
                const bool s = (xi <= 0.0f);
                const bool valley = right && left && s;
                const bool peak   = !right && !left && !s;
                const unsigned ab = __float_as_uint(xi) & 0x7fffffffu;
                kr[j] = (valley || peak)
                          ? (((u64)ab << 32) | (u64)(unsigned)(W - 1 - base - j)) : 0ull;
            }
        }
        u64 mx = 0ull;
        #pragma unroll
        for (int j = 0; j < PT; ++j) if (kr[j] > mx) mx = kr[j];

        // DIAGNOSTIC round loop: exactly RFIX rounds, body identical to R6.
        // Rounds after natural termination are idempotent no-ops (mx==0
        // everywhere -> Mm=Mc=Mp=0 -> no keeps, no kills) so output is
        // bit-identical; the extra rounds measure c_idle via duration slope.
        for (int r = 1; r <= RFIX; ++r) {
            HM[tid + 2] = mx;
            const u64 bal = __ballot(mx != 0ull);
            if ((tid & 63) == 0 && bal) LF = r;    // <=1 store per wave
            __syncthreads();                                   // B1
            const int live = LF; (void)live;       // kept for body parity; unused
            const u64 h0 = HM[2 * c];
            const u64 h1 = HM[2 * c + 1];
            const u64 h2 = HM[2 * c + 2];
            const u64 h3 = HM[2 * c + 3];
            const u64 h4 = HM[2 * c + 4];
            const u64 h5 = HM[2 * c + 5];

            const u64 Mm = h0 > h1 ? h0 : h1;   // chunk c-1 max (0 at edges via pads)
            const u64 Mc = h2 > h3 ? h2 : h3;   // own chunk max
            const u64 Mp = h4 > h5 ? h4 : h5;   // chunk c+1 max
            const int jm = (W - 1) - (int)(Mm & 0xffffffffu);
            const int jc = (W - 1) - (int)(Mc & 0xffffffffu);
            const int jp = (W - 1) - (int)(Mp & 0xffffffffu);

            // push-kill: my live elements suppress neighbor-chunk candidates
            if (Mm != 0ull && mx > Mm) {
                #pragma unroll
                for (int j = 0; j < PT; ++j)
                    if (kr[j] > Mm && ((base + j) - jm) <= D32) KF[c] = r;       // chunk c-1
            }
            if (Mp != 0ull && mx > Mp) {
                #pragma unroll
                for (int j = 0; j < PT; ++j)
                    if (kr[j] > Mp && (jp - (base + j)) <= D32) KF[c + 2] = r;   // chunk c+1
            }
            __syncthreads();                                   // B2
            const int kf0 = KF[c];
            const int kf1 = KF[c + 1];
            const int kf2 = KF[c + 2];
            const bool keep_m = (Mm != 0ull) && (kf0 != r);
            const bool keep_c = (Mc != 0ull) && (kf1 != r);
            const bool keep_p = (Mp != 0ull) && (kf2 != r);

            if (keep_c && (tid & 1) == 0) kept[c] = jc + 1;    // record keeper

            // kill own register keys inside keeper windows (skip if all mine dead)
            if (mx != 0ull) {
                bool changed = false;
                if (keep_m && jm >= base - D32 && jm <= base + PT - 1 + D32) {
                    const int tm = base - jm + D32;
                    #pragma unroll
                    for (int j = 0; j < PT; ++j)
                        if ((unsigned)(tm + j) <= 2u * D32) kr[j] = 0ull;
                    changed = true;
                }
                if (keep_c && jc >= base - D32 && jc <= base + PT - 1 + D32) {
                    const int tc = base - jc + D32;
                    #pragma unroll
                    for (int j = 0; j < PT; ++j)
                        if ((unsigned)(tc + j) <= 2u * D32) kr[j] = 0ull;
                    changed = true;
                }
                if (keep_p && jp >= base - D32 && jp <= base + PT - 1 + D32) {
                    const int tp = base - jp + D32;
                    #pragma unroll
                    for (int j = 0; j < PT; ++j)
                        if ((unsigned)(tp + j) <= 2u * D32) kr[j] = 0ull;
                    changed = true;
                }
                if (changed) {
                    mx = 0ull;
                    #pragma unroll
                    for (int j = 0; j < PT; ++j) if (kr[j] > mx) mx = kr[j];
                }
            }
        }

        // single coalesced output pass
        {
            float4* og4 = (float4*)og;
            #pragma unroll
            for (int v = tid; v < W / 4; v += NT) {
                const int i = v * 4;
                const int k = kept[i >> 5] - 1;   // 4-aligned block stays in one chunk
                float4 o;
                o.x = (k == i    ) ? xs[i    ] : 0.0f;
                o.y = (k == i + 1) ? xs[i + 1] : 0.0f;
                o.z = (k == i + 2) ? xs[i + 2] : 0.0f;
                o.w = (k == i + 3) ? xs[i + 3] : 0.0f;
                og4[v] = o;
            }
        }
    } else {
        // ---------- generic fallback (any dist): proven R1 serial-greedy ----------
        for (int i = tid; i < W; i += NT) og[i] = 0.0f;
        for (int i = tid; i < W; i += NT) {
            const float xi = xs[i];
            const bool right = (i < W - 1) ? (xs[i + 1] > xi) : false;
            const bool left  = (i > 0)     ? (xi <= xs[i - 1]) : true;
            const bool s = (xi <= 0.0f);
            const bool valley = right && left && s;
            const bool peak   = !right && !left && !s;
            const u32 ab = __float_as_uint(xi) & 0x7fffffffu;
            key[i] = (valley || peak) ? (((u64)ab << 32) | (u64)(u32)(W - 1 - i)) : 0ull;
        }
        __syncthreads();

        for (;;) {
            u64 m = 0ull;
            #pragma unroll
            for (int j = 0; j < W / NT; ++j) {
                const u64 k = key[tid + j * NT];
                if (k > m) m = k;
            }
            #pragma unroll
            for (int off = 32; off > 0; off >>= 1) {
                const u64 o = __shfl_down(m, off, 64);
                if (o > m) m = o;
            }
            if ((tid & 63) == 0) red[tid >> 6] = m;
            __syncthreads();
            if (tid == 0) {
                u64 w0 = red[0];
                #pragma unroll
                for (int w2 = 1; w2 < NT / 64; ++w2) if (red[w2] > w0) w0 = red[w2];
                red[0] = w0;
            }
            __syncthreads();
            const u64 win = red[0];
            if (win == 0ull) break;

            const int p = (W - 1) - (int)(win & 0xffffffffu);
            if (tid == 0) og[p] = xs[p];

            int lo = p - dist; lo = lo < 0 ? 0 : lo;
            int hi = p + dist; hi = hi > (W - 1) ? (W - 1) : hi;
            for (int j = lo + tid; j <= hi; j += NT) key[j] = 0ull;
            __syncthreads();
        }
    }
}

extern "C" void kernel_launch(void* const* d_in, const int* in_sizes, int n_in,
                              void* d_out, int out_size, void* d_ws, size_t ws_size,
                              hipStream_t stream) {
    const float* x      = (const float*)d_in[0];
    const int*   dist_p = (const int*)d_in[1];
    float*       out    = (float*)d_out;
    const int nsig = in_sizes[0] / W;   // 128 signals of length 4096
    hipLaunchKernelGGL(extrema_nms_kernel, dim3(nsig), dim3(NT), 0, stream,
                       x, dist_p, out);
}

// Round 11
// 21.077 us; speedup vs baseline: 5.1258x; 5.1258x over previous
//
#include <hip/hip_runtime.h>

typedef unsigned long long u64;
typedef unsigned int u32;

#define W    4096
#define G    4            // signals per block
#define TPS  256          // threads per signal
#define NT   (G * TPS)    // 1024 threads, 16 waves -> 4 waves/SIMD
#define PT   16           // elements per thread
#define NCH  128          // chunks of 32 (== dist fast path)
#define D32  32

__global__ __launch_bounds__(NT) void extrema_nms_multi(
    const float* __restrict__ x,
    const int*   __restrict__ dist_p,
    float*       __restrict__ out,
    int nsig)
{
    // one LDS pool, aliased by fast/slow paths
    __shared__ u64 bigbuf[16408];     // 131 KB

    const int tid = threadIdx.x;
    const int g   = tid >> 8;          // signal group 0..3
    const int t   = tid & (TPS - 1);   // thread within signal
    const int sig = blockIdx.x * G + g;
    const bool on = (sig < nsig);
    const int dist = *dist_p;

    float* XS    = (float*)bigbuf;                    // fast: [G][W] floats
    u64*   HMa   = bigbuf + 8192;                     // fast: [G][260] padded half-maxes
    u32*   p32   = (u32*)(bigbuf + 8192 + 1040);
    u32*   KFa   = p32;                               // fast: [G][130] killflags
    u32*   KEPTa = p32 + G * 130;                     // fast: [G][128] keeper pos+1
    u32*   LFp   = p32 + G * 130 + G * 128;           // fast: block-wide live stamp

    const float* xg = x + (size_t)sig * W;
    float*       og = out + (size_t)sig * W;

    if (dist == D32) {
        // ---- stage x (coalesced float4); off-groups zeroed (=> no extrema) ----
        {
            float4* xs4 = (float4*)(XS + g * W);
            if (on) {
                const float4* xg4 = (const float4*)xg;
                #pragma unroll
                for (int v = t; v < W / 4; v += TPS) xs4[v] = xg4[v];
            } else {
                const float4 z = make_float4(0.f, 0.f, 0.f, 0.f);
                for (int v = t; v < W / 4; v += TPS) xs4[v] = z;
            }
        }
        if (t < 2) { HMa[g * 260 + t] = 0ull; HMa[g * 260 + 258 + t] = 0ull; } // pads
        if (t < 130) KFa[g * 130 + t] = 0;
        if (t < 128) KEPTa[g * 128 + t] = 0;
        if (tid == 0) *LFp = 0;
        __syncthreads();

        const int c    = t >> 1;          // own chunk within signal
        const int base = t * PT;          // first owned element within signal

        // ---- extrema keys in registers (proven R6 build) ----
        u64 kr[PT];
        {
            const float4* xs4 = (const float4*)(XS + g * W);
            const int b4 = t * 4;
            const float4 q0 = xs4[b4], q1 = xs4[b4 + 1], q2 = xs4[b4 + 2], q3 = xs4[b4 + 3];
            float f[PT + 2];
            f[1] = q0.x; f[2] = q0.y; f[3] = q0.z; f[4] = q0.w;
            f[5] = q1.x; f[6] = q1.y; f[7] = q1.z; f[8] = q1.w;
            f[9] = q2.x; f[10] = q2.y; f[11] = q2.z; f[12] = q2.w;
            f[13] = q3.x; f[14] = q3.y; f[15] = q3.z; f[16] = q3.w;
            f[0]      = (base > 0)      ? XS[g * W + base - 1]  : __int_as_float(0x7f800000);
            f[PT + 1] = (base + PT < W) ? XS[g * W + base + PT] : q3.w;
            #pragma unroll
            for (int j = 0; j < PT; ++j) {
                const float xi = f[j + 1];
                const bool right = f[j + 2] > xi;   // pad-right -> false
                const bool left  = xi <= f[j];      // pad-left  -> true
                const bool s = (xi <= 0.0f);
                const bool valley = right && left && s;
                const bool peak   = !right && !left && !s;
                const u32 ab = __float_as_uint(xi) & 0x7fffffffu;
                kr[j] = (valley || peak)
                          ? (((u64)ab << 32) | (u64)(u32)(W - 1 - base - j)) : 0ull;
            }
        }
        u64 mx = 0ull;
        #pragma unroll
        for (int j = 0; j < PT; ++j) if (kr[j] > mx) mx = kr[j];

        // ---- round loop (R6 body; lockstep across 4 signal groups) ----
        int r = 0;
        for (;;) {
            ++r;
            HMa[g * 260 + t + 2] = mx;
            const u64 bal = __ballot(mx != 0ull);
            if ((t & 63) == 0 && bal) *LFp = r;          // any live group stamps
            __syncthreads();                              // B1
            const int live = *LFp;
            const u64 h0 = HMa[g * 260 + 2 * c];
            const u64 h1 = HMa[g * 260 + 2 * c + 1];
            const u64 h2 = HMa[g * 260 + 2 * c + 2];
            const u64 h3 = HMa[g * 260 + 2 * c + 3];
            const u64 h4 = HMa[g * 260 + 2 * c + 4];
            const u64 h5 = HMa[g * 260 + 2 * c + 5];
            if (live != r) break;    // block-uniform: no live group anywhere

            const u64 Mm = h0 > h1 ? h0 : h1;
            const u64 Mc = h2 > h3 ? h2 : h3;
            const u64 Mp = h4 > h5 ? h4 : h5;
            const int jm = (W - 1) - (int)(Mm & 0xffffffffu);
            const int jc = (W - 1) - (int)(Mc & 0xffffffffu);
            const int jp = (W - 1) - (int)(Mp & 0xffffffffu);

            if (Mm != 0ull && mx > Mm) {
                #pragma unroll
                for (int j = 0; j < PT; ++j)
                    if (kr[j] > Mm && ((base + j) - jm) <= D32) KFa[g * 130 + c] = r;
            }
            if (Mp != 0ull && mx > Mp) {
                #pragma unroll
                for (int j = 0; j < PT; ++j)
                    if (kr[j] > Mp && (jp - (base + j)) <= D32) KFa[g * 130 + c + 2] = r;
            }
            __syncthreads();                              // B2
            const u32 kf0 = KFa[g * 130 + c];
            const u32 kf1 = KFa[g * 130 + c + 1];
            const u32 kf2 = KFa[g * 130 + c + 2];
            const bool keep_m = (Mm != 0ull) && (kf0 != (u32)r);
            const bool keep_c = (Mc != 0ull) && (kf1 != (u32)r);
            const bool keep_p = (Mp != 0ull) && (kf2 != (u32)r);

            if (keep_c && (t & 1) == 0) KEPTa[g * 128 + c] = (u32)(jc + 1);

            if (mx != 0ull) {
                bool changed = false;
                if (keep_m && jm >= base - D32 && jm <= base + PT - 1 + D32) {
                    const int tm = base - jm + D32;
                    #pragma unroll
                    for (int j = 0; j < PT; ++j)
                        if ((u32)(tm + j) <= 2u * D32) kr[j] = 0ull;
                    changed = true;
                }
                if (keep_c && jc >= base - D32 && jc <= base + PT - 1 + D32) {
                    const int tc = base - jc + D32;
                    #pragma unroll
                    for (int j = 0; j < PT; ++j)
                        if ((u32)(tc + j) <= 2u * D32) kr[j] = 0ull;
                    changed = true;
                }
                if (keep_p && jp >= base - D32 && jp <= base + PT - 1 + D32) {
                    const int tp = base - jp + D32;
                    #pragma unroll
                    for (int j = 0; j < PT; ++j)
                        if ((u32)(tp + j) <= 2u * D32) kr[j] = 0ull;
                    changed = true;
                }
                if (changed) {
                    mx = 0ull;
                    #pragma unroll
                    for (int j = 0; j < PT; ++j) if (kr[j] > mx) mx = kr[j];
                }
            }
        }

        // ---- coalesced output ----
        if (on) {
            float4* og4 = (float4*)og;
            const float* xsg = XS + g * W;
            #pragma unroll
            for (int v = t; v < W / 4; v += TPS) {
                const int i = v * 4;
                const int k = (int)KEPTa[g * 128 + (i >> 5)] - 1;
                float4 o;
                o.x = (k == i    ) ? xsg[i    ] : 0.0f;
                o.y = (k == i + 1) ? xsg[i + 1] : 0.0f;
                o.z = (k == i + 2) ? xsg[i + 2] : 0.0f;
                o.w = (k == i + 3) ? xsg[i + 3] : 0.0f;
                og4[v] = o;
            }
        }
    } else {
        // ---------- generic fallback (any dist): serial greedy, 4 signals lockstep ----------
        u64* KEY = bigbuf + (size_t)g * W;          // [G][W]
        u64* RED = bigbuf + 16384;                  // [G][4]
        u32* LFA = (u32*)(bigbuf + 16400);

        if (on) for (int i = t; i < W; i += TPS) og[i] = 0.0f;
        for (int i = t; i < W; i += TPS) {
            u64 kv = 0ull;
            if (on) {
                const float xi = xg[i];
                const bool right = (i < W - 1) ? (xg[i + 1] > xi) : false;
                const bool left  = (i > 0)     ? (xi <= xg[i - 1]) : true;
                const bool s = (xi <= 0.0f);
                const bool valley = right && left && s;
                const bool peak   = !right && !left && !s;
                const u32 ab = __float_as_uint(xi) & 0x7fffffffu;
                kv = (valley || peak) ? (((u64)ab << 32) | (u64)(u32)(W - 1 - i)) : 0ull;
            }
            KEY[i] = kv;
        }
        if (tid == 0) *LFA = 0;
        __syncthreads();

        int r = 0;
        for (;;) {
            ++r;
            u64 m = 0ull;
            #pragma unroll
            for (int j = 0; j < W / TPS; ++j) {
                const u64 k = KEY[t + j * TPS];
                if (k > m) m = k;
            }
            #pragma unroll
            for (int off = 32; off > 0; off >>= 1) {
                const u64 o = __shfl_down(m, off, 64);
                if (o > m) m = o;
            }
            if ((t & 63) == 0) RED[g * 4 + (t >> 6)] = m;
            __syncthreads();
            if (t == 0) {
                u64 w0 = RED[g * 4];
                #pragma unroll
                for (int w2 = 1; w2 < 4; ++w2) if (RED[g * 4 + w2] > w0) w0 = RED[g * 4 + w2];
                RED[g * 4] = w0;
                if (w0 != 0ull) *LFA = (u32)r;
            }
            __syncthreads();
            const u64 win = RED[g * 4];
            if (*LFA != (u32)r) break;      // block-uniform termination

            if (win != 0ull) {              // off/finished groups: no-op round
                const int p = (W - 1) - (int)(win & 0xffffffffu);
                if (t == 0) og[p] = xg[p];
                int lo = p - dist; lo = lo < 0 ? 0 : lo;
                int hi = p + dist; hi = hi > (W - 1) ? (W - 1) : hi;
                for (int j = lo + t; j <= hi; j += TPS) KEY[j] = 0ull;
            }
            __syncthreads();
        }
    }
}

extern "C" void kernel_launch(void* const* d_in, const int* in_sizes, int n_in,
                              void* d_out, int out_size, void* d_ws, size_t ws_size,
                              hipStream_t stream) {
    const float* x      = (const float*)d_in[0];
    const int*   dist_p = (const int*)d_in[1];
    float*       out    = (float*)d_out;
    const int nsig = in_sizes[0] / W;   // 128 signals of length 4096
    const int nblk = (nsig + G - 1) / G;
    hipLaunchKernelGGL(extrema_nms_multi, dim3(nblk), dim3(NT), 0, stream,
                       x, dist_p, out, nsig);
}